// Round 6
// baseline (339.545 us; speedup 1.0000x reference)
//
#include <hip/hip_runtime.h>
#include <cmath>

#define NA 76725
#define NCLS 80
#define NB 4
#define KC 512
#define MPC 100
#define MT 100
#define TT 128          // anchors per scan tile
#define NTILE 600       // ceil(NA/TT)
#define NSLOTP 600      // tile-slots per column (= tiles)
#define NSLOTPAD 1024   // padded for pair prefix-sum with 512 threads
#define PADN 76800      // NA padded (fallback scan loop, multiple of 512)
#define CAP 4096        // per-column LDS candidate capacity
#define SLOT 16         // entries per slot (128 anchors, p=0.0227 -> mean 2.9, P(>16)~3e-8)
#define THRESH_LOGIT 2.0f

struct Dims { float d[5 * 9 * 2]; };

// ---- helpers -------------------------------------------------------------

__device__ __forceinline__ unsigned keyof(float x) {
    unsigned u = __float_as_uint(x);
    return u ^ ((u & 0x80000000u) ? 0xFFFFFFFFu : 0x80000000u);
}
__device__ __forceinline__ float unkey(unsigned k) {
    unsigned u = (k & 0x80000000u) ? (k ^ 0x80000000u) : ~k;
    return __uint_as_float(u);
}
__device__ __forceinline__ float sigmoidf_dev(float x) {
    if (x >= 0.f) return 1.f / (1.f + expf(-x));
    float e = expf(x);
    return e / (1.f + e);
}
__device__ __forceinline__ unsigned long long compose(unsigned key, int a) {
    return ((unsigned long long)key << 32) | (unsigned long long)(0xFFFFFFFFu - (unsigned)a);
}

__device__ __forceinline__ float4 decode_box(float4 p, int a, const Dims& dims) {
    const int base[5] = {0, 57600, 72000, 75600, 76500};
    const int fw[5] = {80, 40, 20, 10, 5};
    const float strd[5] = {8.f, 16.f, 32.f, 64.f, 128.f};
    int l;
    if (a < 57600) l = 0;
    else if (a < 72000) l = 1;
    else if (a < 75600) l = 2;
    else if (a < 76500) l = 3;
    else l = 4;
    int i = a - base[l];
    int cell = i / 9, k = i - cell * 9;
    int x = cell % fw[l], y = cell / fw[l];
    float cx = ((float)x + 0.5f) * strd[l];
    float cy = ((float)y + 0.5f) * strd[l];
    float aw = dims.d[(l * 9 + k) * 2 + 0];
    float ah = dims.d[(l * 9 + k) * 2 + 1];
    float bx = __fmul_rn(p.x, 0.1f), by = __fmul_rn(p.y, 0.1f);
    float bw = __fmul_rn(p.z, 0.2f), bh = __fmul_rn(p.w, 0.2f);
    float4 o;
    o.x = __fadd_rn(__fmul_rn(bx, aw), cx);
    o.y = __fadd_rn(__fmul_rn(by, ah), cy);
    o.z = __fmul_rn(expf(bw), aw);
    o.w = __fmul_rn(expf(bh), ah);
    return o;
}

// ---- kernel 1: candidate filter — 4x-batched loads, LDS-atomic rank ------
// 4 float4 loads issued before any use -> 4 loads in flight per thread
// (vmcnt(3..0) staggered waits) to attack the memory-latency floor.
// candbuf layout is block-contiguous: slot region = (b*NTILE+tix)*NCLS*SLOT,
// so a block's scattered hit-writes land in one hot 10 KB region.

__global__ __launch_bounds__(256) void scan_kernel(const float* __restrict__ pred,
                                                   unsigned long long* __restrict__ candbuf,
                                                   int* __restrict__ counts2) {
    __shared__ int cnt[NCLS];
    const int blk = blockIdx.x;
    const int b = blk / NTILE, tix = blk - b * NTILE;
    const int t0 = tix * TT;
    int nrow = NA - t0; if (nrow > TT) nrow = TT;

    if (threadIdx.x < NCLS) cnt[threadIdx.x] = 0;
    __syncthreads();

    const float4* src = reinterpret_cast<const float4*>(pred + ((size_t)b * NA + t0) * 84);
    const int nv = nrow * 21;
    unsigned long long* slotbase = candbuf + (size_t)(b * NTILE + tix) * NCLS * SLOT;

    #define PROC(v, idx) do {                                                  \
        const int row_ = (idx) / 21, chunk_ = (idx) - row_ * 21;               \
        if (chunk_ != 20) {                                                    \
            const int a_ = t0 + row_, cbase_ = chunk_ * 4;                     \
            const float vals_[4] = {(v).x, (v).y, (v).z, (v).w};               \
            _Pragma("unroll")                                                  \
            for (int q_ = 0; q_ < 4; ++q_) {                                   \
                if (vals_[q_] > THRESH_LOGIT) {                                \
                    const int c_ = cbase_ + q_;                                \
                    const int p_ = atomicAdd(&cnt[c_], 1);                     \
                    if (p_ < SLOT)                                             \
                        slotbase[c_ * SLOT + p_] = compose(keyof(vals_[q_]), a_); \
                }                                                              \
            }                                                                  \
        }                                                                      \
    } while (0)

    int i = threadIdx.x;
    for (; i + 768 < nv; i += 1024) {
        const float4 v0 = src[i];
        const float4 v1 = src[i + 256];
        const float4 v2 = src[i + 512];
        const float4 v3 = src[i + 768];
        PROC(v0, i); PROC(v1, i + 256); PROC(v2, i + 512); PROC(v3, i + 768);
    }
    for (; i < nv; i += 256) {
        const float4 v = src[i];
        PROC(v, i);
    }
    #undef PROC

    __syncthreads();
    if (threadIdx.x < NCLS)
        counts2[(size_t)(b * NCLS + threadIdx.x) * NSLOTP + tix] = cnt[threadIdx.x];
}

// ---- per-block reversed (high->low) histogram threshold find -------------
// shfl-based scan. Block size must be 512.

__device__ __forceinline__ void find_bin(int* hist, int bins, int remaining,
                                         int* sh3, int* wsum) {
    const int tid = threadIdx.x;
    const int lane = tid & 63, wv = tid >> 6;
    const int nit = (bins + 511) >> 9;
    int lsum = 0;
    for (int q = 0; q < nit; ++q) {
        int rr = tid * nit + q;
        if (rr < bins) lsum += hist[bins - 1 - rr];
    }
    int acc = lsum;
    #pragma unroll
    for (int off = 1; off < 64; off <<= 1) {
        int x = __shfl_up(acc, off);
        if (lane >= off) acc += x;
    }
    if (lane == 63) wsum[wv] = acc;
    __syncthreads();
    int base = 0;
    for (int w = 0; w < wv; ++w) base += wsum[w];
    int run = base + acc - lsum;     // exclusive prefix (count in higher bins)
    for (int q = 0; q < nit; ++q) {
        int rr = tid * nit + q;
        if (rr < bins) {
            int h = hist[bins - 1 - rr];
            if (run < remaining && remaining <= run + h) { sh3[0] = bins - 1 - rr; sh3[1] = run; sh3[2] = h; }
            run += h;
        }
    }
    __syncthreads();
}

// ---- kernel 2: fused top-512 + decode + NMS build + greedy resolve -------
// One 512-thread block per (batch,class) column. Phases:
//  1. slot-count prefix sum  2. gather candidates -> LDS  3. exact 8-pass
//  radix + bitonic sort 512  4. decode boxes -> LDS  5. 512x512 IOU mask
//  in LDS (aliases dead cand[])  6. wave-parallel greedy  7. compact top-100.
// Fallback (overflow / count outside [KC,CAP]): exact full column scan.

__global__ __launch_bounds__(512) void topnms_kernel(const float* __restrict__ pred,
                                                     const unsigned long long* __restrict__ candbuf,
                                                     const int* __restrict__ counts2,
                                                     float4* __restrict__ col_boxes,
                                                     float* __restrict__ col_scores, Dims dims) {
    const int col = blockIdx.x;
    const int b = col / NCLS, cc = col - b * NCLS;
    const int tid = threadIdx.x;
    const int lane = tid & 63, wv = tid >> 6;

    __shared__ unsigned long long cand[CAP];   // 32 KiB (aliases hist4k & mask)
    __shared__ int hist[256];                  //  1 KiB
    __shared__ unsigned long long buf[KC];     //  4 KiB
    __shared__ int scnt[NSLOTPAD];             //  4 KiB
    __shared__ int spfx[NSLOTPAD];             //  4 KiB
    __shared__ float y1[KC], x1[KC], y2[KC], x2[KC], ar[KC], sc[KC];   // 12 KiB
    __shared__ unsigned long long keep0w[8], keepw[8];
    __shared__ int wordpfx[9];
    __shared__ int sel[MPC];
    __shared__ int sh3[3];
    __shared__ int wsum[8];
    __shared__ int gcount, eqtaken, totsh, ovfsh;
    __shared__ int wcnt[8];
    int* hist4k = (int*)cand;                         // fallback-only alias
    unsigned long long* maskl = cand;                 // mask alias (cand dead by then)

    // ---- phase 1: slot counts (coalesced), overflow check, pair prefix-sum
    if (tid == 0) { totsh = 0; ovfsh = 0; }
    for (int i = tid; i < NSLOTPAD; i += 512)
        scnt[i] = (i < NSLOTP) ? counts2[(size_t)col * NSLOTP + i] : 0;
    __syncthreads();

    const int c0s = scnt[2 * tid], c1s = scnt[2 * tid + 1];
    if (c0s > SLOT || c1s > SLOT) ovfsh = 1;
    const int pair = c0s + c1s;
    int acc = pair;
    #pragma unroll
    for (int off = 1; off < 64; off <<= 1) {
        int x = __shfl_up(acc, off);
        if (lane >= off) acc += x;
    }
    if (lane == 63) wsum[wv] = acc;
    __syncthreads();
    int base = 0;
    for (int w = 0; w < wv; ++w) base += wsum[w];
    const int excl = base + acc - pair;
    spfx[2 * tid] = excl;
    spfx[2 * tid + 1] = excl + c0s;
    if (tid == 511) totsh = base + acc;
    __syncthreads();

    const int tot = totsh;
    const bool fastok = (!ovfsh) && tot >= KC && tot <= CAP;
    int nc = -1;

    if (fastok) {
        // ---- phase 2: gather; keep entry (e,q) iff q < scnt[e]
        const size_t colbase = (size_t)(b * NTILE) * (NCLS * SLOT) + (size_t)cc * SLOT;
        for (int i = tid; i < NSLOTP * SLOT; i += 512) {
            const int e = i >> 4, q = i & (SLOT - 1);
            const unsigned long long v = candbuf[colbase + (size_t)e * (NCLS * SLOT) + q];
            if (q < scnt[e]) cand[spfx[e] + q] = v;
        }
        nc = tot;
        __syncthreads();
    } else {
        // ---- exact fallback: strided on-the-fly keys ----
        const float* colp = pred + (size_t)b * NA * 84 + cc;
        for (int i = tid; i < 4096; i += 512) hist4k[i] = 0;
        __syncthreads();
        for (int a = tid; a < NA; a += 512)
            atomicAdd(&hist4k[keyof(colp[(size_t)a * 84]) >> 20], 1);
        __syncthreads();
        find_bin(hist4k, 4096, KC, sh3, wsum);
        const int bsel = sh3[0], above = sh3[1], ceq1 = sh3[2];
        const int ncand = above + ceq1;

        if (ncand <= CAP) {
            const unsigned fk = ((unsigned)bsel) << 20;
            if (tid == 0) gcount = 0;
            __syncthreads();
            for (int a = tid; a < NA; a += 512) {
                unsigned k = keyof(colp[(size_t)a * 84]);
                if (k >= fk) { int p = atomicAdd(&gcount, 1); cand[p] = compose(k, a); }
            }
            __syncthreads();
            nc = gcount;
        } else {
            // massive ties in one 12-bit bin: refine threshold to exact key
            unsigned prefix = ((unsigned)bsel) << 20;
            int remaining = KC - above;

            for (int i = tid; i < 4096; i += 512) hist4k[i] = 0;
            __syncthreads();
            for (int a = tid; a < NA; a += 512) {
                unsigned k = keyof(colp[(size_t)a * 84]);
                if ((k & 0xFFF00000u) == prefix) atomicAdd(&hist4k[(k >> 8) & 4095], 1);
            }
            __syncthreads();
            find_bin(hist4k, 4096, remaining, sh3, wsum);
            prefix |= ((unsigned)sh3[0]) << 8;
            remaining -= sh3[1];

            if (tid < 256) hist[tid] = 0;
            __syncthreads();
            for (int a = tid; a < NA; a += 512) {
                unsigned k = keyof(colp[(size_t)a * 84]);
                if ((k & 0xFFFFFF00u) == prefix) atomicAdd(&hist[k & 255], 1);
            }
            __syncthreads();
            find_bin(hist, 256, remaining, sh3, wsum);
            prefix |= (unsigned)sh3[0];
            remaining -= sh3[1];

            const unsigned K = prefix;
            const int cgt = KC - remaining;
            const int need = remaining;
            if (tid == 0) { gcount = 0; eqtaken = 0; }
            __syncthreads();
            for (int bs = 0; bs < PADN; bs += 512) {
                int a = bs + tid;
                unsigned key = (a < NA) ? keyof(colp[(size_t)a * 84]) : 0u;
                if (a < NA && key > K) {
                    int p = atomicAdd(&gcount, 1);
                    buf[p] = compose(key, a);
                }
                bool eq = (key == K) && (a < NA);
                unsigned long long m = __ballot(eq);
                if (lane == 0) wcnt[wv] = __popcll(m);
                __syncthreads();
                int off = eqtaken;
                for (int w = 0; w < wv; ++w) off += wcnt[w];
                int rank = off + __popcll(m & ((1ull << lane) - 1ull));
                if (eq && rank < need)
                    buf[cgt + rank] = compose(K, a);
                __syncthreads();
                if (tid == 0) {
                    int s = 0;
                    for (int w = 0; w < 8; ++w) s += wcnt[w];
                    eqtaken += s;
                }
                __syncthreads();
            }
            nc = -1;   // buf filled directly
        }
    }

    if (nc >= 0) {
        // ---- phase 3a: 8-pass byte radix -> exact 512th, compact into buf
        unsigned long long cpre = 0ull;
        int rem512 = KC;
        for (int pass = 0; pass < 8; ++pass) {
            const int shift = 56 - 8 * pass;
            const unsigned long long mdone = pass ? ((~0ull) << (shift + 8)) : 0ull;
            if (tid < 256) hist[tid] = 0;
            __syncthreads();
            for (int t = tid; t < nc; t += 512) {
                unsigned long long k = cand[t];
                if ((k & mdone) == cpre) atomicAdd(&hist[(int)((k >> shift) & 255)], 1);
            }
            __syncthreads();
            find_bin(hist, 256, rem512, sh3, wsum);
            cpre |= ((unsigned long long)(unsigned)sh3[0]) << shift;
            rem512 -= sh3[1];
            __syncthreads();
        }
        if (tid == 0) gcount = 0;
        __syncthreads();
        for (int t = tid; t < nc; t += 512) {
            unsigned long long k = cand[t];
            if (k >= cpre) { int p = atomicAdd(&gcount, 1); buf[p] = k; }
        }
        __syncthreads();
    }

    // ---- phase 3b: bitonic sort 512 desc by composite
    for (int k2 = 2; k2 <= KC; k2 <<= 1) {
        for (int j = k2 >> 1; j > 0; j >>= 1) {
            __syncthreads();
            {
                int i = tid, ixj = i ^ j;
                if (ixj > i) {
                    unsigned long long A = buf[i], B = buf[ixj];
                    bool up = (i & k2) == 0;
                    if (up ? (A < B) : (A > B)) { buf[i] = B; buf[ixj] = A; }
                }
            }
        }
    }
    __syncthreads();

    // ---- phase 4: decode boxes + scores into LDS; keep0 ballot
    {
        const unsigned long long v = buf[tid];
        const unsigned key = (unsigned)(v >> 32);
        const int a = (int)(0xFFFFFFFFu - (unsigned)(v & 0xFFFFFFFFu));
        const float s = sigmoidf_dev(unkey(key));
        sc[tid] = s;
        const float4 p4 = *reinterpret_cast<const float4*>(pred + ((size_t)b * NA + a) * 84 + 80);
        const float4 bx = decode_box(p4, a, dims);
        y1[tid] = bx.x; x1[tid] = bx.y; y2[tid] = bx.z; x2[tid] = bx.w;
        ar[tid] = __fmul_rn(fmaxf(__fsub_rn(bx.z, bx.x), 0.f),
                            fmaxf(__fsub_rn(bx.w, bx.y), 0.f));
        const unsigned long long m = __ballot(s > 0.05f);
        if (lane == 0) keep0w[tid >> 6] = m;
    }
    __syncthreads();

    // ---- phase 5: 512x512 suppression mask into LDS (aliases cand)
    {
        float jy1[8], jx1[8], jy2[8], jx2[8], jar[8];
        #pragma unroll
        for (int w = 0; w < 8; ++w) {
            int j = (w << 6) + lane;
            jy1[w] = y1[j]; jx1[w] = x1[j]; jy2[w] = y2[j]; jx2[w] = x2[j]; jar[w] = ar[j];
        }
        for (int k = 0; k < 64; ++k) {
            const int i = wv + 8 * k;               // covers 0..511
            const float iy1 = y1[i], ix1 = x1[i], iy2 = y2[i], ix2 = x2[i], iar = ar[i];
            unsigned long long row[8];
            #pragma unroll
            for (int w = 0; w < 8; ++w) {
                unsigned long long m = 0ull;
                if (((w << 6) + 63) > i) {
                    const int j = (w << 6) + lane;
                    float ih = fmaxf(__fsub_rn(fminf(iy2, jy2[w]), fmaxf(iy1, jy1[w])), 0.f);
                    float iw = fmaxf(__fsub_rn(fminf(ix2, jx2[w]), fmaxf(ix1, jx1[w])), 0.f);
                    float inter = __fmul_rn(ih, iw);
                    float uni = __fsub_rn(__fadd_rn(iar, jar[w]), inter);
                    m = __ballot((uni > 0.f) && (inter > __fmul_rn(0.5f, uni)) && (j > i));
                }
                row[w] = m;
            }
            unsigned long long v = row[0];
            v = (lane == 1) ? row[1] : v;
            v = (lane == 2) ? row[2] : v;
            v = (lane == 3) ? row[3] : v;
            v = (lane == 4) ? row[4] : v;
            v = (lane == 5) ? row[5] : v;
            v = (lane == 6) ? row[6] : v;
            v = (lane == 7) ? row[7] : v;
            if (lane < 8) maskl[i * 8 + lane] = v;
        }
    }
    __syncthreads();

    // ---- phase 6: greedy resolve, wave 0, 8-lane word-parallel
    if (wv == 0) {
        const int w8 = lane & 7;
        const unsigned long long kww = keep0w[w8];
        unsigned long long remw = 0ull;
        for (int ib = 0; ib < KC; ib += 8) {
            unsigned long long rows[8];
            #pragma unroll
            for (int u = 0; u < 8; ++u) rows[u] = maskl[(ib + u) * 8 + w8];
            #pragma unroll
            for (int u = 0; u < 8; ++u) {
                const int i = ib + u, W = i >> 6, t = i & 63;
                const unsigned long long remW = __shfl(remw, W);
                const unsigned long long kwW = __shfl(kww, W);
                if (((kwW >> t) & 1ull) && !((remW >> t) & 1ull)) remw |= rows[u];
            }
        }
        if (lane < 8) keepw[w8] = kww & ~remw;
    }
    __syncthreads();
    if (tid == 0) {
        int s = 0;
        #pragma unroll
        for (int w = 0; w < 8; ++w) { wordpfx[w] = s; s += __popcll(keepw[w]); }
        wordpfx[8] = s;
    }
    __syncthreads();

    // ---- phase 7: compact top-100, write out
    const int nkept = wordpfx[8];
    {
        const int t = tid;
        const unsigned long long w = keepw[t >> 6];
        const int l = t & 63;
        const bool kp = (w >> l) & 1ull;
        const int kb = wordpfx[t >> 6] + __popcll(w & ((1ull << l) - 1ull));
        if (kp) {
            if (kb < MPC) sel[kb] = t;
        } else {
            const int nb = t - kb;
            if (nkept + nb < MPC) sel[nkept + nb] = t;
        }
    }
    __syncthreads();
    if (tid < MPC) {
        int t = sel[tid];
        bool kp = (keepw[t >> 6] >> (t & 63)) & 1ull;
        col_scores[col * MPC + tid] = kp ? sc[t] : 0.f;
        col_boxes[col * MPC + tid] = make_float4(y1[t], x1[t], y2[t], x2[t]);
    }
}

// ---- kernel 3: per-batch combine — 1024 threads, register keys -----------

__global__ __launch_bounds__(1024) void combine_kernel(const float4* __restrict__ col_boxes,
                                                       const float* __restrict__ col_scores,
                                                       float* __restrict__ out) {
    const int b = blockIdx.x, tid = threadIdx.x;
    const int wv = tid >> 6, lane = tid & 63;
    __shared__ int hist[256];
    __shared__ unsigned long long cand[128];
    __shared__ int sh3[3];
    __shared__ int gcnt, eqtaken;
    __shared__ int wcnt[16];
    __shared__ int wsc[16];

    const int NTOT = NCLS * MPC;     // 8000
    unsigned sck[8];
    #pragma unroll
    for (int q = 0; q < 8; ++q) {
        const int t = (q << 10) + tid;
        sck[q] = (t < NTOT) ? __float_as_uint(col_scores[b * NTOT + t]) : 0u;
    }

    unsigned prefix = 0;
    int remaining = MT, ceq = 0;
    #pragma unroll 1
    for (int pass = 0; pass < 4; ++pass) {
        const int shift = 24 - 8 * pass;
        const unsigned mdone = pass ? (0xFFFFFFFFu << (shift + 8)) : 0u;
        if (tid < 256) hist[tid] = 0;
        __syncthreads();
        #pragma unroll
        for (int q = 0; q < 8; ++q) {
            const int t = (q << 10) + tid;
            if (t < NTOT && (sck[q] & mdone) == prefix)
                atomicAdd(&hist[(sck[q] >> shift) & 255], 1);
        }
        __syncthreads();
        int lsum = (tid < 256) ? hist[255 - tid] : 0;
        int acc2 = lsum;
        #pragma unroll
        for (int off = 1; off < 64; off <<= 1) {
            int x = __shfl_up(acc2, off);
            if (lane >= off) acc2 += x;
        }
        if (lane == 63) wsc[wv] = acc2;
        __syncthreads();
        int base2 = 0;
        for (int w = 0; w < wv; ++w) base2 += wsc[w];
        int run = base2 + acc2 - lsum;
        if (tid < 256 && run < remaining && remaining <= run + lsum) { sh3[0] = 255 - tid; sh3[1] = run; sh3[2] = lsum; }
        __syncthreads();
        prefix |= ((unsigned)sh3[0]) << shift;
        remaining -= sh3[1];
        ceq = sh3[2];
        __syncthreads();
    }
    const unsigned S = prefix;
    const int cgt = MT - remaining;

    if (tid == 0) { gcnt = 0; eqtaken = 0; }
    if (tid < 128) cand[tid] = 0ull;
    __syncthreads();
    #pragma unroll
    for (int q = 0; q < 8; ++q) {
        const int t = (q << 10) + tid;
        if (t < NTOT && sck[q] > S) {
            int p = atomicAdd(&gcnt, 1);
            cand[p] = ((unsigned long long)sck[q] << 32) |
                      (unsigned long long)(0xFFFFFFFFu - (unsigned)t);
        }
    }
    __syncthreads();

    if (ceq == remaining) {
        #pragma unroll
        for (int q = 0; q < 8; ++q) {
            const int t = (q << 10) + tid;
            if (t < NTOT && sck[q] == S) {
                int p = atomicAdd(&eqtaken, 1);
                cand[cgt + p] = ((unsigned long long)S << 32) |
                                (unsigned long long)(0xFFFFFFFFu - (unsigned)t);
            }
        }
        __syncthreads();
    } else {
        #pragma unroll 1
        for (int q = 0; q < 8; ++q) {
            const int t = (q << 10) + tid;
            const bool eq = (t < NTOT) && (sck[q] == S);
            unsigned long long m = __ballot(eq);
            if (lane == 0) wcnt[wv] = __popcll(m);
            __syncthreads();
            int off = eqtaken;
            for (int w = 0; w < wv; ++w) off += wcnt[w];
            int rank = off + __popcll(m & ((1ull << lane) - 1ull));
            if (eq && rank < remaining)
                cand[cgt + rank] = ((unsigned long long)S << 32) |
                                   (unsigned long long)(0xFFFFFFFFu - (unsigned)t);
            __syncthreads();
            if (tid == 0) {
                int s = 0;
                for (int w = 0; w < 16; ++w) s += wcnt[w];
                eqtaken += s;
            }
            __syncthreads();
        }
    }

    for (int k2 = 2; k2 <= 128; k2 <<= 1) {
        for (int j = k2 >> 1; j > 0; j >>= 1) {
            __syncthreads();
            if (tid < 128) {
                int i = tid, ixj = i ^ j;
                if (ixj > i) {
                    unsigned long long A = cand[i], B = cand[ixj];
                    bool up = (i & k2) == 0;
                    if (up ? (A < B) : (A > B)) { cand[i] = B; cand[ixj] = A; }
                }
            }
        }
    }
    __syncthreads();
    if (tid == 0) gcnt = 0;
    __syncthreads();
    if (tid < MT) {
        unsigned long long v = cand[tid];
        float s = __uint_as_float((unsigned)(v >> 32));
        int f = (int)(0xFFFFFFFFu - (unsigned)(v & 0xFFFFFFFFu));
        bool valid = (s > 0.f);
        int cl = 0, p = 0;
        float4 bx = make_float4(0.f, 0.f, 0.f, 0.f);
        if (valid) {
            cl = f / MPC;
            p = f - cl * MPC;
            float4 raw = col_boxes[((size_t)b * NCLS + cl) * MPC + p];
            bx.x = fminf(fmaxf(raw.x, 0.f), 1.f);
            bx.y = fminf(fmaxf(raw.y, 0.f), 1.f);
            bx.z = fminf(fmaxf(raw.z, 0.f), 1.f);
            bx.w = fminf(fmaxf(raw.w, 0.f), 1.f);
            atomicAdd(&gcnt, 1);
        }
        int o = b * MT + tid;
        out[o * 4 + 0] = bx.x;
        out[o * 4 + 1] = bx.y;
        out[o * 4 + 2] = bx.z;
        out[o * 4 + 3] = bx.w;
        out[NB * MT * 4 + o] = valid ? s : 0.f;
        out[NB * MT * 5 + o] = valid ? (float)cl : 0.f;
    }
    __syncthreads();
    if (tid == 0) out[NB * MT * 6 + b] = (float)gcnt;
}

// ---- launch --------------------------------------------------------------

extern "C" void kernel_launch(void* const* d_in, const int* in_sizes, int n_in,
                              void* d_out, int out_size, void* d_ws, size_t ws_size,
                              hipStream_t stream) {
    const float* pred = (const float*)d_in[1];
    float* out = (float*)d_out;
    char* ws = (char*)d_ws;

    Dims dims;
    const double ratios[3] = {0.5, 1.0, 2.0};
    for (int l = 0; l < 5; ++l) {
        double side = (double)(1 << (l + 5));
        double area = side * side;
        for (int ri = 0; ri < 3; ++ri) {
            double ah = sqrt(area / ratios[ri]);
            double aw = area / ah;
            for (int si = 0; si < 3; ++si) {
                double s = pow(2.0, (double)si / 3.0);
                dims.d[(l * 9 + ri * 3 + si) * 2 + 0] = (float)(s * aw);
                dims.d[(l * 9 + ri * 3 + si) * 2 + 1] = (float)(s * ah);
            }
        }
    }

    const size_t SZ_CAND = (size_t)NB * NCLS * NSLOTP * SLOT * 8;   // 24,576,000
    const size_t SZ_CNT  = (size_t)NB * NCLS * NSLOTP * 4;          //     768,000
    const size_t SZ_CB   = (size_t)NB * NCLS * MPC * 16;            //     512,000

    unsigned long long* candbuf    = (unsigned long long*)(ws);
    int*                counts2    = (int*)(ws + SZ_CAND);
    float4*             col_boxes  = (float4*)(ws + SZ_CAND + SZ_CNT);
    float*              col_scores = (float*)(ws + SZ_CAND + SZ_CNT + SZ_CB);

    scan_kernel<<<NB * NTILE, 256, 0, stream>>>(pred, candbuf, counts2);
    topnms_kernel<<<NB * NCLS, 512, 0, stream>>>(pred, candbuf, counts2, col_boxes, col_scores, dims);
    combine_kernel<<<NB, 1024, 0, stream>>>(col_boxes, col_scores, out);
}

// Round 7
// 304.574 us; speedup vs baseline: 1.1148x; 1.1148x over previous
//
#include <hip/hip_runtime.h>
#include <cmath>

#define NA 76725
#define NCLS 80
#define NB 4
#define KC 512
#define MPC 100
#define MT 100
#define TT 256          // anchors per scan tile
#define NTILE 300       // ceil(NA/TT)
#define NSLOTP 300      // tile-slots per column (= tiles)
#define PADN 76800      // NA padded (fallback scan loop, multiple of 512)
#define NCAND 1024      // per-column LDS candidate capacity (tot ~ 823 +- 28)
#define SLOT 16         // entries per slot (256 anchors, p=0.0107 -> mean 2.75, P(>16)~6e-9)
#define SPLIT 8         // build blocks per column
#define THRESH_LOGIT 2.3f   // 512th largest logit = 2.473 +- 0.016 -> 11 sigma margin

struct Dims { float d[5 * 9 * 2]; };

// ---- helpers -------------------------------------------------------------

__device__ __forceinline__ unsigned keyof(float x) {
    unsigned u = __float_as_uint(x);
    return u ^ ((u & 0x80000000u) ? 0xFFFFFFFFu : 0x80000000u);
}
__device__ __forceinline__ float unkey(unsigned k) {
    unsigned u = (k & 0x80000000u) ? (k ^ 0x80000000u) : ~k;
    return __uint_as_float(u);
}
__device__ __forceinline__ float sigmoidf_dev(float x) {
    if (x >= 0.f) return 1.f / (1.f + expf(-x));
    float e = expf(x);
    return e / (1.f + e);
}
__device__ __forceinline__ unsigned long long compose(unsigned key, int a) {
    return ((unsigned long long)key << 32) | (unsigned long long)(0xFFFFFFFFu - (unsigned)a);
}

__device__ __forceinline__ float4 decode_box(float4 p, int a, const Dims& dims) {
    const int base[5] = {0, 57600, 72000, 75600, 76500};
    const int fw[5] = {80, 40, 20, 10, 5};
    const float strd[5] = {8.f, 16.f, 32.f, 64.f, 128.f};
    int l;
    if (a < 57600) l = 0;
    else if (a < 72000) l = 1;
    else if (a < 75600) l = 2;
    else if (a < 76500) l = 3;
    else l = 4;
    int i = a - base[l];
    int cell = i / 9, k = i - cell * 9;
    int x = cell % fw[l], y = cell / fw[l];
    float cx = ((float)x + 0.5f) * strd[l];
    float cy = ((float)y + 0.5f) * strd[l];
    float aw = dims.d[(l * 9 + k) * 2 + 0];
    float ah = dims.d[(l * 9 + k) * 2 + 1];
    float bx = __fmul_rn(p.x, 0.1f), by = __fmul_rn(p.y, 0.1f);
    float bw = __fmul_rn(p.z, 0.2f), bh = __fmul_rn(p.w, 0.2f);
    float4 o;
    o.x = __fadd_rn(__fmul_rn(bx, aw), cx);
    o.y = __fadd_rn(__fmul_rn(by, ah), cy);
    o.z = __fmul_rn(expf(bw), aw);
    o.w = __fmul_rn(expf(bh), ah);
    return o;
}

// ---- kernel 1: candidate filter — register test + LDS-atomic rank --------
// (round-5 proven structure; only TT/SLOT/threshold changed)

__global__ __launch_bounds__(256) void scan_kernel(const float* __restrict__ pred,
                                                   unsigned long long* __restrict__ candbuf,
                                                   int* __restrict__ counts2) {
    __shared__ int cnt[NCLS];
    const int blk = blockIdx.x;
    const int b = blk / NTILE, tix = blk - b * NTILE;
    const int t0 = tix * TT;
    int nrow = NA - t0; if (nrow > TT) nrow = TT;

    if (threadIdx.x < NCLS) cnt[threadIdx.x] = 0;
    __syncthreads();

    const float4* src = reinterpret_cast<const float4*>(pred + ((size_t)b * NA + t0) * 84);
    const int nv = nrow * 21;
    // candbuf[(col*NSLOTP + tix)*SLOT + p], col = b*NCLS + c
    unsigned long long* slotbase = candbuf + ((size_t)(b * NCLS) * NSLOTP + tix) * SLOT;
    for (int i = threadIdx.x; i < nv; i += 256) {
        const float4 v = src[i];
        const int row = i / 21, chunk = i - row * 21;
        if (chunk == 20) continue;                  // box fields (decoded in topk2)
        const int a = t0 + row, cbase = chunk * 4;
        const float vals[4] = {v.x, v.y, v.z, v.w};
        #pragma unroll
        for (int q = 0; q < 4; ++q) {
            if (vals[q] > THRESH_LOGIT) {
                const int c = cbase + q;
                const int p = atomicAdd(&cnt[c], 1);
                if (p < SLOT)
                    slotbase[(size_t)c * NSLOTP * SLOT + p] = compose(keyof(vals[q]), a);
            }
        }
    }
    __syncthreads();
    if (threadIdx.x < NCLS)
        counts2[(size_t)(b * NCLS + threadIdx.x) * NSLOTP + tix] = cnt[threadIdx.x];
}

// ---- per-block reversed (high->low) histogram threshold find -------------
// shfl-based scan. Block size must be 512. (fallback-only)

__device__ __forceinline__ void find_bin(int* hist, int bins, int remaining,
                                         int* sh3, int* wsum) {
    const int tid = threadIdx.x;
    const int lane = tid & 63, wv = tid >> 6;
    const int nit = (bins + 511) >> 9;
    int lsum = 0;
    for (int q = 0; q < nit; ++q) {
        int rr = tid * nit + q;
        if (rr < bins) lsum += hist[bins - 1 - rr];
    }
    int acc = lsum;
    #pragma unroll
    for (int off = 1; off < 64; off <<= 1) {
        int x = __shfl_up(acc, off);
        if (lane >= off) acc += x;
    }
    if (lane == 63) wsum[wv] = acc;
    __syncthreads();
    int base = 0;
    for (int w = 0; w < wv; ++w) base += wsum[w];
    int run = base + acc - lsum;     // exclusive prefix (count in higher bins)
    for (int q = 0; q < nit; ++q) {
        int rr = tid * nit + q;
        if (rr < bins) {
            int h = hist[bins - 1 - rr];
            if (run < remaining && remaining <= run + h) { sh3[0] = bins - 1 - rr; sh3[1] = run; sh3[2] = h; }
            run += h;
        }
    }
    __syncthreads();
}

// ---- kernel 2: per-column exact top-512 + fused box decode ---------------
// Fast path (radix-free): gather <=1024 candidates (zero-padded), ONE
// bitonic-1024 sort desc by unique composite, top 512 = prefix. Epilogue
// decodes the 512 boxes into sel_boxes. Fallbacks (overflow / tot outside
// [KC,NCAND]): exact full-column scan (proven r5/r6 machinery).
// LDS: hist4k[4096] block aliases {cand[1024] | scnt[512] | spfx[512]}.

__global__ __launch_bounds__(512) void topk2_kernel(const float* __restrict__ pred,
                                                    const unsigned long long* __restrict__ candbuf,
                                                    const int* __restrict__ counts2,
                                                    float* __restrict__ top_score,
                                                    float4* __restrict__ sel_boxes, Dims dims) {
    const int col = blockIdx.x;
    const int b = col / NCLS, cc = col - b * NCLS;
    const int tid = threadIdx.x;
    const int lane = tid & 63, wv = tid >> 6;

    __shared__ int hist4k[4096];               // 16 KiB block (aliased)
    __shared__ unsigned long long buf[KC];     //  4 KiB (fallback-B output)
    __shared__ int hist[256];                  //  1 KiB
    __shared__ int sh3[3];
    __shared__ int wsum[8];
    __shared__ int gcount, eqtaken, totsh, ovfsh;
    __shared__ int wcnt[8];
    unsigned long long* cand = (unsigned long long*)hist4k;   // [0..1023]  8 KiB
    int* scnt = hist4k + 2048;                                // [512]      2 KiB
    int* spfx = hist4k + 2560;                                // [512]      2 KiB

    // ---- phase 1: slot counts, overflow check, shfl prefix-sum (512 slots)
    if (tid == 0) { totsh = 0; ovfsh = 0; }
    int lsum = (tid < NSLOTP) ? counts2[(size_t)col * NSLOTP + tid] : 0;
    scnt[tid] = lsum;
    if (lsum > SLOT) ovfsh = 1;
    int acc = lsum;
    #pragma unroll
    for (int off = 1; off < 64; off <<= 1) {
        int x = __shfl_up(acc, off);
        if (lane >= off) acc += x;
    }
    if (lane == 63) wsum[wv] = acc;
    __syncthreads();
    int base = 0;
    for (int w = 0; w < wv; ++w) base += wsum[w];
    spfx[tid] = base + acc - lsum;
    if (tid == 511) totsh = base + acc;
    __syncthreads();

    const int tot = totsh;
    const bool fastok = (!ovfsh) && tot >= KC && tot <= NCAND;
    int mode = 0;    // 0: sorted result in cand (bitonic-1024), 1: in buf (bitonic-512)

    if (fastok) {
        // ---- phase 2: zero-pad + coalesced gather
        cand[tid] = 0ull; cand[tid + 512] = 0ull;
        __syncthreads();
        const unsigned long long* src = candbuf + (size_t)col * NSLOTP * SLOT;
        for (int i = tid; i < NSLOTP * SLOT; i += 512) {
            const int e = i >> 4, q = i & (SLOT - 1);
            const unsigned long long v = src[i];
            if (q < scnt[e]) cand[spfx[e] + q] = v;
        }
        __syncthreads();
    } else {
        // ---- exact fallback: strided on-the-fly keys ----
        const float* colp = pred + (size_t)b * NA * 84 + cc;
        for (int i = tid; i < 4096; i += 512) hist4k[i] = 0;
        __syncthreads();
        for (int a = tid; a < NA; a += 512)
            atomicAdd(&hist4k[keyof(colp[(size_t)a * 84]) >> 20], 1);
        __syncthreads();
        find_bin(hist4k, 4096, KC, sh3, wsum);
        const int bsel = sh3[0], above = sh3[1], ceq1 = sh3[2];
        const int ncand = above + ceq1;

        if (ncand <= NCAND) {
            // fallback-A: gather into cand (zero-padded), sort with bitonic-1024
            const unsigned fk = ((unsigned)bsel) << 20;
            if (tid == 0) gcount = 0;
            cand[tid] = 0ull; cand[tid + 512] = 0ull;
            __syncthreads();
            for (int a = tid; a < NA; a += 512) {
                unsigned k = keyof(colp[(size_t)a * 84]);
                if (k >= fk) { int p = atomicAdd(&gcount, 1); cand[p] = compose(k, a); }
            }
            __syncthreads();
        } else {
            // fallback-B: massive ties — refine threshold to exact key
            mode = 1;
            unsigned prefix = ((unsigned)bsel) << 20;
            int remaining = KC - above;

            for (int i = tid; i < 4096; i += 512) hist4k[i] = 0;
            __syncthreads();
            for (int a = tid; a < NA; a += 512) {
                unsigned k = keyof(colp[(size_t)a * 84]);
                if ((k & 0xFFF00000u) == prefix) atomicAdd(&hist4k[(k >> 8) & 4095], 1);
            }
            __syncthreads();
            find_bin(hist4k, 4096, remaining, sh3, wsum);
            prefix |= ((unsigned)sh3[0]) << 8;
            remaining -= sh3[1];

            if (tid < 256) hist[tid] = 0;
            __syncthreads();
            for (int a = tid; a < NA; a += 512) {
                unsigned k = keyof(colp[(size_t)a * 84]);
                if ((k & 0xFFFFFF00u) == prefix) atomicAdd(&hist[k & 255], 1);
            }
            __syncthreads();
            find_bin(hist, 256, remaining, sh3, wsum);
            prefix |= (unsigned)sh3[0];
            remaining -= sh3[1];

            const unsigned K = prefix;
            const int cgt = KC - remaining;
            const int need = remaining;
            if (tid == 0) { gcount = 0; eqtaken = 0; }
            __syncthreads();
            for (int bs = 0; bs < PADN; bs += 512) {
                int a = bs + tid;
                unsigned key = (a < NA) ? keyof(colp[(size_t)a * 84]) : 0u;
                if (a < NA && key > K) {
                    int p = atomicAdd(&gcount, 1);
                    buf[p] = compose(key, a);
                }
                bool eq = (key == K) && (a < NA);
                unsigned long long m = __ballot(eq);
                if (lane == 0) wcnt[wv] = __popcll(m);
                __syncthreads();
                int off = eqtaken;
                for (int w = 0; w < wv; ++w) off += wcnt[w];
                int rank = off + __popcll(m & ((1ull << lane) - 1ull));
                if (eq && rank < need)
                    buf[cgt + rank] = compose(K, a);
                __syncthreads();
                if (tid == 0) {
                    int s = 0;
                    for (int w = 0; w < 8; ++w) s += wcnt[w];
                    eqtaken += s;
                }
                __syncthreads();
            }
        }
    }

    // ---- phase 3: sort desc (composite unique -> total order)
    if (mode == 0) {
        // bitonic-1024 over cand, 512 threads x 2 elements
        for (int k2 = 2; k2 <= NCAND; k2 <<= 1) {
            for (int j = k2 >> 1; j > 0; j >>= 1) {
                __syncthreads();
                for (int i = tid; i < NCAND; i += 512) {
                    int ixj = i ^ j;
                    if (ixj > i) {
                        unsigned long long A = cand[i], B = cand[ixj];
                        bool up = (i & k2) == 0;
                        if (up ? (A < B) : (A > B)) { cand[i] = B; cand[ixj] = A; }
                    }
                }
            }
        }
    } else {
        // bitonic-512 over buf
        for (int k2 = 2; k2 <= KC; k2 <<= 1) {
            for (int j = k2 >> 1; j > 0; j >>= 1) {
                __syncthreads();
                {
                    int i = tid, ixj = i ^ j;
                    if (ixj > i) {
                        unsigned long long A = buf[i], B = buf[ixj];
                        bool up = (i & k2) == 0;
                        if (up ? (A < B) : (A > B)) { buf[i] = B; buf[ixj] = A; }
                    }
                }
            }
        }
    }
    __syncthreads();

    // ---- epilogue: write scores + decode the 512 selected boxes
    {
        const unsigned long long v = (mode == 0) ? cand[tid] : buf[tid];
        const unsigned key = (unsigned)(v >> 32);
        const int a = (int)(0xFFFFFFFFu - (unsigned)(v & 0xFFFFFFFFu));
        top_score[col * KC + tid] = sigmoidf_dev(unkey(key));
        const float4 p4 = *reinterpret_cast<const float4*>(pred + ((size_t)b * NA + a) * 84 + 80);
        sel_boxes[(size_t)col * KC + tid] = decode_box(p4, a, dims);
    }
}

// ---- kernel 3a: NMS suppression-matrix build (SPLIT=8, 512 thr) ----------

__global__ __launch_bounds__(512) void nms_build_kernel(const float4* __restrict__ sel_boxes,
                                                        unsigned long long* __restrict__ maskbuf) {
    const int blk = blockIdx.x;
    const int col = blk >> 3, part = blk & 7;
    const int tid = threadIdx.x, wave = tid >> 6, lane = tid & 63;
    __shared__ float y1[KC], x1[KC], y2[KC], x2[KC], ar[KC];   // 10 KiB

    for (int t = tid; t < KC; t += 512) {
        float4 bx = sel_boxes[(size_t)col * KC + t];
        y1[t] = bx.x; x1[t] = bx.y; y2[t] = bx.z; x2[t] = bx.w;
        ar[t] = __fmul_rn(fmaxf(__fsub_rn(bx.z, bx.x), 0.f),
                          fmaxf(__fsub_rn(bx.w, bx.y), 0.f));
    }
    __syncthreads();

    float jy1[8], jx1[8], jy2[8], jx2[8], jar[8];
    #pragma unroll
    for (int w = 0; w < 8; ++w) {
        int j = (w << 6) + lane;
        jy1[w] = y1[j]; jx1[w] = x1[j]; jy2[w] = y2[j]; jx2[w] = x2[j]; jar[w] = ar[j];
    }

    for (int k = 0; k < 8; ++k) {
        const int i = part + SPLIT * (wave + 8 * k);   // i == part (mod 8), covers 0..511
        const float iy1 = y1[i], ix1 = x1[i], iy2 = y2[i], ix2 = x2[i], iar = ar[i];
        unsigned long long row[8];
        #pragma unroll
        for (int w = 0; w < 8; ++w) {
            unsigned long long m = 0ull;
            if (((w << 6) + 63) > i) {
                const int j = (w << 6) + lane;
                float ih = fmaxf(__fsub_rn(fminf(iy2, jy2[w]), fmaxf(iy1, jy1[w])), 0.f);
                float iw = fmaxf(__fsub_rn(fminf(ix2, jx2[w]), fmaxf(ix1, jx1[w])), 0.f);
                float inter = __fmul_rn(ih, iw);
                float uni = __fsub_rn(__fadd_rn(iar, jar[w]), inter);
                m = __ballot((uni > 0.f) && (inter > __fmul_rn(0.5f, uni)) && (j > i));
            }
            row[w] = m;
        }
        unsigned long long v = row[0];
        v = (lane == 1) ? row[1] : v;
        v = (lane == 2) ? row[2] : v;
        v = (lane == 3) ? row[3] : v;
        v = (lane == 4) ? row[4] : v;
        v = (lane == 5) ? row[5] : v;
        v = (lane == 6) ? row[6] : v;
        v = (lane == 7) ? row[7] : v;
        if (lane < 8) maskbuf[((size_t)col * KC + i) * 8 + lane] = v;
    }
}

// ---- kernel 3b: NMS wave-parallel greedy resolve + compaction ------------

__global__ __launch_bounds__(256) void nms_resolve_kernel(const float4* __restrict__ sel_boxes,
                                                          const float* __restrict__ top_score,
                                                          const unsigned long long* __restrict__ maskbuf,
                                                          float4* __restrict__ col_boxes,
                                                          float* __restrict__ col_scores) {
    const int col = blockIdx.x;
    const int tid = threadIdx.x, wv = tid >> 6, lane = tid & 63;
    __shared__ unsigned long long mask[KC * 8];      // 32 KiB
    __shared__ float y1[KC], x1[KC], y2[KC], x2[KC], sc[KC];   // 10 KiB
    __shared__ unsigned long long keep0w[8], keepw[8];
    __shared__ int wordpfx[9];
    __shared__ int sel[MPC];

    {
        const unsigned long long* src = maskbuf + (size_t)col * KC * 8;
        for (int m = tid; m < KC * 8; m += 256) mask[m] = src[m];
    }
    for (int t = tid; t < KC; t += 256) {
        float4 bx = sel_boxes[(size_t)col * KC + t];
        y1[t] = bx.x; x1[t] = bx.y; y2[t] = bx.z; x2[t] = bx.w;
        const float s = top_score[col * KC + t];
        sc[t] = s;
        const unsigned long long m = __ballot(s > 0.05f);
        if (lane == 0) keep0w[t >> 6] = m;
    }
    __syncthreads();

    // greedy resolve, wave 0, 8-lane word-parallel, 8-row prefetch
    if (wv == 0) {
        const int w8 = lane & 7;
        const unsigned long long kww = keep0w[w8];
        unsigned long long remw = 0ull;
        for (int ib = 0; ib < KC; ib += 8) {
            unsigned long long rows[8];
            #pragma unroll
            for (int u = 0; u < 8; ++u) rows[u] = mask[(ib + u) * 8 + w8];
            #pragma unroll
            for (int u = 0; u < 8; ++u) {
                const int i = ib + u, W = i >> 6, t = i & 63;
                const unsigned long long remW = __shfl(remw, W);
                const unsigned long long kwW = __shfl(kww, W);
                if (((kwW >> t) & 1ull) && !((remW >> t) & 1ull)) remw |= rows[u];
            }
        }
        if (lane < 8) keepw[w8] = kww & ~remw;
    }
    __syncthreads();
    if (tid == 0) {
        int s = 0;
        #pragma unroll
        for (int w = 0; w < 8; ++w) { wordpfx[w] = s; s += __popcll(keepw[w]); }
        wordpfx[8] = s;
    }
    __syncthreads();

    const int nkept = wordpfx[8];
    for (int t = tid; t < KC; t += 256) {
        const unsigned long long w = keepw[t >> 6];
        const int l = t & 63;
        const bool kp = (w >> l) & 1ull;
        const int kb = wordpfx[t >> 6] + __popcll(w & ((1ull << l) - 1ull));
        if (kp) {
            if (kb < MPC) sel[kb] = t;
        } else {
            const int nb = t - kb;
            if (nkept + nb < MPC) sel[nkept + nb] = t;
        }
    }
    __syncthreads();
    if (tid < MPC) {
        int t = sel[tid];
        bool kp = (keepw[t >> 6] >> (t & 63)) & 1ull;
        col_scores[col * MPC + tid] = kp ? sc[t] : 0.f;
        col_boxes[col * MPC + tid] = make_float4(y1[t], x1[t], y2[t], x2[t]);
    }
}

// ---- kernel 4: per-batch combine — 1024 threads, register keys -----------

__global__ __launch_bounds__(1024) void combine_kernel(const float4* __restrict__ col_boxes,
                                                       const float* __restrict__ col_scores,
                                                       float* __restrict__ out) {
    const int b = blockIdx.x, tid = threadIdx.x;
    const int wv = tid >> 6, lane = tid & 63;
    __shared__ int hist[256];
    __shared__ unsigned long long cand[128];
    __shared__ int sh3[3];
    __shared__ int gcnt, eqtaken;
    __shared__ int wcnt[16];
    __shared__ int wsc[16];

    const int NTOT = NCLS * MPC;     // 8000
    unsigned sck[8];
    #pragma unroll
    for (int q = 0; q < 8; ++q) {
        const int t = (q << 10) + tid;
        sck[q] = (t < NTOT) ? __float_as_uint(col_scores[b * NTOT + t]) : 0u;
    }

    unsigned prefix = 0;
    int remaining = MT, ceq = 0;
    #pragma unroll 1
    for (int pass = 0; pass < 4; ++pass) {
        const int shift = 24 - 8 * pass;
        const unsigned mdone = pass ? (0xFFFFFFFFu << (shift + 8)) : 0u;
        if (tid < 256) hist[tid] = 0;
        __syncthreads();
        #pragma unroll
        for (int q = 0; q < 8; ++q) {
            const int t = (q << 10) + tid;
            if (t < NTOT && (sck[q] & mdone) == prefix)
                atomicAdd(&hist[(sck[q] >> shift) & 255], 1);
        }
        __syncthreads();
        int lsum = (tid < 256) ? hist[255 - tid] : 0;
        int acc2 = lsum;
        #pragma unroll
        for (int off = 1; off < 64; off <<= 1) {
            int x = __shfl_up(acc2, off);
            if (lane >= off) acc2 += x;
        }
        if (lane == 63) wsc[wv] = acc2;
        __syncthreads();
        int base2 = 0;
        for (int w = 0; w < wv; ++w) base2 += wsc[w];
        int run = base2 + acc2 - lsum;
        if (tid < 256 && run < remaining && remaining <= run + lsum) { sh3[0] = 255 - tid; sh3[1] = run; sh3[2] = lsum; }
        __syncthreads();
        prefix |= ((unsigned)sh3[0]) << shift;
        remaining -= sh3[1];
        ceq = sh3[2];
        __syncthreads();
    }
    const unsigned S = prefix;
    const int cgt = MT - remaining;

    if (tid == 0) { gcnt = 0; eqtaken = 0; }
    if (tid < 128) cand[tid] = 0ull;
    __syncthreads();
    #pragma unroll
    for (int q = 0; q < 8; ++q) {
        const int t = (q << 10) + tid;
        if (t < NTOT && sck[q] > S) {
            int p = atomicAdd(&gcnt, 1);
            cand[p] = ((unsigned long long)sck[q] << 32) |
                      (unsigned long long)(0xFFFFFFFFu - (unsigned)t);
        }
    }
    __syncthreads();

    if (ceq == remaining) {
        #pragma unroll
        for (int q = 0; q < 8; ++q) {
            const int t = (q << 10) + tid;
            if (t < NTOT && sck[q] == S) {
                int p = atomicAdd(&eqtaken, 1);
                cand[cgt + p] = ((unsigned long long)S << 32) |
                                (unsigned long long)(0xFFFFFFFFu - (unsigned)t);
            }
        }
        __syncthreads();
    } else {
        #pragma unroll 1
        for (int q = 0; q < 8; ++q) {
            const int t = (q << 10) + tid;
            const bool eq = (t < NTOT) && (sck[q] == S);
            unsigned long long m = __ballot(eq);
            if (lane == 0) wcnt[wv] = __popcll(m);
            __syncthreads();
            int off = eqtaken;
            for (int w = 0; w < wv; ++w) off += wcnt[w];
            int rank = off + __popcll(m & ((1ull << lane) - 1ull));
            if (eq && rank < remaining)
                cand[cgt + rank] = ((unsigned long long)S << 32) |
                                   (unsigned long long)(0xFFFFFFFFu - (unsigned)t);
            __syncthreads();
            if (tid == 0) {
                int s = 0;
                for (int w = 0; w < 16; ++w) s += wcnt[w];
                eqtaken += s;
            }
            __syncthreads();
        }
    }

    for (int k2 = 2; k2 <= 128; k2 <<= 1) {
        for (int j = k2 >> 1; j > 0; j >>= 1) {
            __syncthreads();
            if (tid < 128) {
                int i = tid, ixj = i ^ j;
                if (ixj > i) {
                    unsigned long long A = cand[i], B = cand[ixj];
                    bool up = (i & k2) == 0;
                    if (up ? (A < B) : (A > B)) { cand[i] = B; cand[ixj] = A; }
                }
            }
        }
    }
    __syncthreads();
    if (tid == 0) gcnt = 0;
    __syncthreads();
    if (tid < MT) {
        unsigned long long v = cand[tid];
        float s = __uint_as_float((unsigned)(v >> 32));
        int f = (int)(0xFFFFFFFFu - (unsigned)(v & 0xFFFFFFFFu));
        bool valid = (s > 0.f);
        int cl = 0, p = 0;
        float4 bx = make_float4(0.f, 0.f, 0.f, 0.f);
        if (valid) {
            cl = f / MPC;
            p = f - cl * MPC;
            float4 raw = col_boxes[((size_t)b * NCLS + cl) * MPC + p];
            bx.x = fminf(fmaxf(raw.x, 0.f), 1.f);
            bx.y = fminf(fmaxf(raw.y, 0.f), 1.f);
            bx.z = fminf(fmaxf(raw.z, 0.f), 1.f);
            bx.w = fminf(fmaxf(raw.w, 0.f), 1.f);
            atomicAdd(&gcnt, 1);
        }
        int o = b * MT + tid;
        out[o * 4 + 0] = bx.x;
        out[o * 4 + 1] = bx.y;
        out[o * 4 + 2] = bx.z;
        out[o * 4 + 3] = bx.w;
        out[NB * MT * 4 + o] = valid ? s : 0.f;
        out[NB * MT * 5 + o] = valid ? (float)cl : 0.f;
    }
    __syncthreads();
    if (tid == 0) out[NB * MT * 6 + b] = (float)gcnt;
}

// ---- launch --------------------------------------------------------------

extern "C" void kernel_launch(void* const* d_in, const int* in_sizes, int n_in,
                              void* d_out, int out_size, void* d_ws, size_t ws_size,
                              hipStream_t stream) {
    const float* pred = (const float*)d_in[1];
    float* out = (float*)d_out;
    char* ws = (char*)d_ws;

    Dims dims;
    const double ratios[3] = {0.5, 1.0, 2.0};
    for (int l = 0; l < 5; ++l) {
        double side = (double)(1 << (l + 5));
        double area = side * side;
        for (int ri = 0; ri < 3; ++ri) {
            double ah = sqrt(area / ratios[ri]);
            double aw = area / ah;
            for (int si = 0; si < 3; ++si) {
                double s = pow(2.0, (double)si / 3.0);
                dims.d[(l * 9 + ri * 3 + si) * 2 + 0] = (float)(s * aw);
                dims.d[(l * 9 + ri * 3 + si) * 2 + 1] = (float)(s * ah);
            }
        }
    }

    const size_t SZ_CAND = (size_t)NB * NCLS * NSLOTP * SLOT * 8;   // 12,288,000
    const size_t SZ_CNT  = (size_t)NB * NCLS * NSLOTP * 4;          //     384,000
    const size_t SZ_SC   = (size_t)NB * NCLS * KC * 4;              //     655,360
    const size_t SZ_SEL  = (size_t)NB * NCLS * KC * 16;             //   2,621,440
    const size_t SZ_CB   = (size_t)NB * NCLS * MPC * 16;            //     512,000

    unsigned long long* candbuf    = (unsigned long long*)(ws);
    int*                counts2    = (int*)(ws + SZ_CAND);
    float*              top_score  = (float*)(ws + SZ_CAND + SZ_CNT);
    float4*             sel_boxes  = (float4*)(ws + SZ_CAND + SZ_CNT + SZ_SC);
    float4*             col_boxes  = (float4*)(ws + SZ_CAND + SZ_CNT + SZ_SC + SZ_SEL);
    float*              col_scores = (float*)(ws + SZ_CAND + SZ_CNT + SZ_SC + SZ_SEL + SZ_CB);
    // maskbuf (10.48 MB) aliases candbuf (12.29 MB) — candidates dead after topk2.
    unsigned long long* maskbuf    = (unsigned long long*)(ws);

    scan_kernel<<<NB * NTILE, 256, 0, stream>>>(pred, candbuf, counts2);
    topk2_kernel<<<NB * NCLS, 512, 0, stream>>>(pred, candbuf, counts2, top_score, sel_boxes, dims);
    nms_build_kernel<<<NB * NCLS * SPLIT, 512, 0, stream>>>(sel_boxes, maskbuf);
    nms_resolve_kernel<<<NB * NCLS, 256, 0, stream>>>(sel_boxes, top_score, maskbuf, col_boxes, col_scores);
    combine_kernel<<<NB, 1024, 0, stream>>>(col_boxes, col_scores, out);
}

// Round 8
// 297.768 us; speedup vs baseline: 1.1403x; 1.0229x over previous
//
#include <hip/hip_runtime.h>
#include <cmath>

#define NA 76725
#define NCLS 80
#define NB 4
#define KC 512
#define MPC 100
#define MT 100
#define TT 256          // anchors per scan tile
#define NTILE 300       // ceil(NA/TT)
#define NSLOTP 300      // tile-slots per column (= tiles)
#define PADN 76800      // NA padded (fallback scan loop, multiple of 512)
#define NCAND 1024      // per-column LDS candidate capacity (tot ~ 823 +- 28)
#define SLOT 16         // entries per slot (256 anchors, p=0.0107 -> mean 2.75, P(>16)~6e-9)
#define SPLIT 8         // build blocks per column
#define THRESH_LOGIT 2.3f   // 512th largest logit = 2.473 +- 0.016 -> 11 sigma margin

struct Dims { float d[5 * 9 * 2]; };

// ---- helpers -------------------------------------------------------------

__device__ __forceinline__ unsigned keyof(float x) {
    unsigned u = __float_as_uint(x);
    return u ^ ((u & 0x80000000u) ? 0xFFFFFFFFu : 0x80000000u);
}
__device__ __forceinline__ float unkey(unsigned k) {
    unsigned u = (k & 0x80000000u) ? (k ^ 0x80000000u) : ~k;
    return __uint_as_float(u);
}
__device__ __forceinline__ float sigmoidf_dev(float x) {
    if (x >= 0.f) return 1.f / (1.f + expf(-x));
    float e = expf(x);
    return e / (1.f + e);
}
__device__ __forceinline__ unsigned long long compose(unsigned key, int a) {
    return ((unsigned long long)key << 32) | (unsigned long long)(0xFFFFFFFFu - (unsigned)a);
}

__device__ __forceinline__ float4 decode_box(float4 p, int a, const Dims& dims) {
    const int base[5] = {0, 57600, 72000, 75600, 76500};
    const int fw[5] = {80, 40, 20, 10, 5};
    const float strd[5] = {8.f, 16.f, 32.f, 64.f, 128.f};
    int l;
    if (a < 57600) l = 0;
    else if (a < 72000) l = 1;
    else if (a < 75600) l = 2;
    else if (a < 76500) l = 3;
    else l = 4;
    int i = a - base[l];
    int cell = i / 9, k = i - cell * 9;
    int x = cell % fw[l], y = cell / fw[l];
    float cx = ((float)x + 0.5f) * strd[l];
    float cy = ((float)y + 0.5f) * strd[l];
    float aw = dims.d[(l * 9 + k) * 2 + 0];
    float ah = dims.d[(l * 9 + k) * 2 + 1];
    float bx = __fmul_rn(p.x, 0.1f), by = __fmul_rn(p.y, 0.1f);
    float bw = __fmul_rn(p.z, 0.2f), bh = __fmul_rn(p.w, 0.2f);
    float4 o;
    o.x = __fadd_rn(__fmul_rn(bx, aw), cx);
    o.y = __fadd_rn(__fmul_rn(by, ah), cy);
    o.z = __fmul_rn(expf(bw), aw);
    o.w = __fmul_rn(expf(bh), ah);
    return o;
}

// ---- kernel 1: candidate filter — pure-load loop + LDS staging -----------
// Hits are staged in LDS (atomic rank, order-insensitive) so the streaming
// load loop contains NO global stores (vmcnt stays load-only -> full MLP).
// After the barrier, the <=1280-entry hit buffer is flushed to candbuf in
// coalesced 128B bursts. True counts recorded; topk2 falls back on overflow.

__global__ __launch_bounds__(256) void scan_kernel(const float* __restrict__ pred,
                                                   unsigned long long* __restrict__ candbuf,
                                                   int* __restrict__ counts2) {
    __shared__ int cnt[NCLS];                             // 320 B
    __shared__ unsigned long long hitbuf[NCLS * SLOT];    // 10 KiB
    const int blk = blockIdx.x;
    const int b = blk / NTILE, tix = blk - b * NTILE;
    const int t0 = tix * TT;
    int nrow = NA - t0; if (nrow > TT) nrow = TT;

    if (threadIdx.x < NCLS) cnt[threadIdx.x] = 0;
    __syncthreads();

    const float4* src = reinterpret_cast<const float4*>(pred + ((size_t)b * NA + t0) * 84);
    const int nv = nrow * 21;

    #define PROC(v, idx) do {                                                  \
        const int row_ = (idx) / 21, chunk_ = (idx) - row_ * 21;               \
        if (chunk_ != 20) {                                                    \
            const int a_ = t0 + row_, cbase_ = chunk_ * 4;                     \
            const float vals_[4] = {(v).x, (v).y, (v).z, (v).w};               \
            _Pragma("unroll")                                                  \
            for (int q_ = 0; q_ < 4; ++q_) {                                   \
                if (vals_[q_] > THRESH_LOGIT) {                                \
                    const int c_ = cbase_ + q_;                                \
                    const int p_ = atomicAdd(&cnt[c_], 1);                     \
                    if (p_ < SLOT)                                             \
                        hitbuf[c_ * SLOT + p_] = compose(keyof(vals_[q_]), a_);\
                }                                                              \
            }                                                                  \
        }                                                                      \
    } while (0)

    int i = threadIdx.x;
    for (; i + 768 < nv; i += 1024) {
        const float4 v0 = src[i];
        const float4 v1 = src[i + 256];
        const float4 v2 = src[i + 512];
        const float4 v3 = src[i + 768];
        PROC(v0, i); PROC(v1, i + 256); PROC(v2, i + 512); PROC(v3, i + 768);
    }
    for (; i < nv; i += 256) {
        const float4 v = src[i];
        PROC(v, i);
    }
    #undef PROC
    __syncthreads();

    // ---- flush: coalesced write-out of staged hits + counts
    // candbuf[((b*NCLS + c)*NSLOTP + tix)*SLOT + q]
    for (int e = threadIdx.x; e < NCLS * SLOT; e += 256) {
        const int c = e >> 4, q = e & (SLOT - 1);
        if (q < cnt[c])
            candbuf[(((size_t)(b * NCLS + c)) * NSLOTP + tix) * SLOT + q] = hitbuf[e];
    }
    if (threadIdx.x < NCLS)
        counts2[(size_t)(b * NCLS + threadIdx.x) * NSLOTP + tix] = cnt[threadIdx.x];
}

// ---- per-block reversed (high->low) histogram threshold find -------------
// shfl-based scan. Block size must be 512. (fallback-only)

__device__ __forceinline__ void find_bin(int* hist, int bins, int remaining,
                                         int* sh3, int* wsum) {
    const int tid = threadIdx.x;
    const int lane = tid & 63, wv = tid >> 6;
    const int nit = (bins + 511) >> 9;
    int lsum = 0;
    for (int q = 0; q < nit; ++q) {
        int rr = tid * nit + q;
        if (rr < bins) lsum += hist[bins - 1 - rr];
    }
    int acc = lsum;
    #pragma unroll
    for (int off = 1; off < 64; off <<= 1) {
        int x = __shfl_up(acc, off);
        if (lane >= off) acc += x;
    }
    if (lane == 63) wsum[wv] = acc;
    __syncthreads();
    int base = 0;
    for (int w = 0; w < wv; ++w) base += wsum[w];
    int run = base + acc - lsum;     // exclusive prefix (count in higher bins)
    for (int q = 0; q < nit; ++q) {
        int rr = tid * nit + q;
        if (rr < bins) {
            int h = hist[bins - 1 - rr];
            if (run < remaining && remaining <= run + h) { sh3[0] = bins - 1 - rr; sh3[1] = run; sh3[2] = h; }
            run += h;
        }
    }
    __syncthreads();
}

// ---- kernel 2: per-column exact top-512 + fused box decode ---------------
// Fast path (radix-free): gather <=1024 candidates (zero-padded), ONE
// bitonic-1024 sort desc by unique composite, top 512 = prefix. Epilogue
// decodes the 512 boxes into sel_boxes. Fallbacks (overflow / tot outside
// [KC,NCAND]): exact full-column scan (proven machinery).
// LDS: hist4k[4096] block aliases {cand[1024] | scnt[512] | spfx[512]}.

__global__ __launch_bounds__(512) void topk2_kernel(const float* __restrict__ pred,
                                                    const unsigned long long* __restrict__ candbuf,
                                                    const int* __restrict__ counts2,
                                                    float* __restrict__ top_score,
                                                    float4* __restrict__ sel_boxes, Dims dims) {
    const int col = blockIdx.x;
    const int b = col / NCLS, cc = col - b * NCLS;
    const int tid = threadIdx.x;
    const int lane = tid & 63, wv = tid >> 6;

    __shared__ int hist4k[4096];               // 16 KiB block (aliased)
    __shared__ unsigned long long buf[KC];     //  4 KiB (fallback-B output)
    __shared__ int hist[256];                  //  1 KiB
    __shared__ int sh3[3];
    __shared__ int wsum[8];
    __shared__ int gcount, eqtaken, totsh, ovfsh;
    __shared__ int wcnt[8];
    unsigned long long* cand = (unsigned long long*)hist4k;   // [0..1023]  8 KiB
    int* scnt = hist4k + 2048;                                // [512]      2 KiB
    int* spfx = hist4k + 2560;                                // [512]      2 KiB

    // ---- phase 1: slot counts, overflow check, shfl prefix-sum (512 slots)
    if (tid == 0) { totsh = 0; ovfsh = 0; }
    int lsum = (tid < NSLOTP) ? counts2[(size_t)col * NSLOTP + tid] : 0;
    scnt[tid] = lsum;
    if (lsum > SLOT) ovfsh = 1;
    int acc = lsum;
    #pragma unroll
    for (int off = 1; off < 64; off <<= 1) {
        int x = __shfl_up(acc, off);
        if (lane >= off) acc += x;
    }
    if (lane == 63) wsum[wv] = acc;
    __syncthreads();
    int base = 0;
    for (int w = 0; w < wv; ++w) base += wsum[w];
    spfx[tid] = base + acc - lsum;
    if (tid == 511) totsh = base + acc;
    __syncthreads();

    const int tot = totsh;
    const bool fastok = (!ovfsh) && tot >= KC && tot <= NCAND;
    int mode = 0;    // 0: sorted result in cand (bitonic-1024), 1: in buf (bitonic-512)

    if (fastok) {
        // ---- phase 2: zero-pad + coalesced gather
        cand[tid] = 0ull; cand[tid + 512] = 0ull;
        __syncthreads();
        const unsigned long long* src = candbuf + (size_t)col * NSLOTP * SLOT;
        for (int i = tid; i < NSLOTP * SLOT; i += 512) {
            const int e = i >> 4, q = i & (SLOT - 1);
            const unsigned long long v = src[i];
            if (q < scnt[e]) cand[spfx[e] + q] = v;
        }
        __syncthreads();
    } else {
        // ---- exact fallback: strided on-the-fly keys ----
        const float* colp = pred + (size_t)b * NA * 84 + cc;
        for (int i = tid; i < 4096; i += 512) hist4k[i] = 0;
        __syncthreads();
        for (int a = tid; a < NA; a += 512)
            atomicAdd(&hist4k[keyof(colp[(size_t)a * 84]) >> 20], 1);
        __syncthreads();
        find_bin(hist4k, 4096, KC, sh3, wsum);
        const int bsel = sh3[0], above = sh3[1], ceq1 = sh3[2];
        const int ncand = above + ceq1;

        if (ncand <= NCAND) {
            // fallback-A: gather into cand (zero-padded), sort with bitonic-1024
            const unsigned fk = ((unsigned)bsel) << 20;
            if (tid == 0) gcount = 0;
            cand[tid] = 0ull; cand[tid + 512] = 0ull;
            __syncthreads();
            for (int a = tid; a < NA; a += 512) {
                unsigned k = keyof(colp[(size_t)a * 84]);
                if (k >= fk) { int p = atomicAdd(&gcount, 1); cand[p] = compose(k, a); }
            }
            __syncthreads();
        } else {
            // fallback-B: massive ties — refine threshold to exact key
            mode = 1;
            unsigned prefix = ((unsigned)bsel) << 20;
            int remaining = KC - above;

            for (int i = tid; i < 4096; i += 512) hist4k[i] = 0;
            __syncthreads();
            for (int a = tid; a < NA; a += 512) {
                unsigned k = keyof(colp[(size_t)a * 84]);
                if ((k & 0xFFF00000u) == prefix) atomicAdd(&hist4k[(k >> 8) & 4095], 1);
            }
            __syncthreads();
            find_bin(hist4k, 4096, remaining, sh3, wsum);
            prefix |= ((unsigned)sh3[0]) << 8;
            remaining -= sh3[1];

            if (tid < 256) hist[tid] = 0;
            __syncthreads();
            for (int a = tid; a < NA; a += 512) {
                unsigned k = keyof(colp[(size_t)a * 84]);
                if ((k & 0xFFFFFF00u) == prefix) atomicAdd(&hist[k & 255], 1);
            }
            __syncthreads();
            find_bin(hist, 256, remaining, sh3, wsum);
            prefix |= (unsigned)sh3[0];
            remaining -= sh3[1];

            const unsigned K = prefix;
            const int cgt = KC - remaining;
            const int need = remaining;
            if (tid == 0) { gcount = 0; eqtaken = 0; }
            __syncthreads();
            for (int bs = 0; bs < PADN; bs += 512) {
                int a = bs + tid;
                unsigned key = (a < NA) ? keyof(colp[(size_t)a * 84]) : 0u;
                if (a < NA && key > K) {
                    int p = atomicAdd(&gcount, 1);
                    buf[p] = compose(key, a);
                }
                bool eq = (key == K) && (a < NA);
                unsigned long long m = __ballot(eq);
                if (lane == 0) wcnt[wv] = __popcll(m);
                __syncthreads();
                int off = eqtaken;
                for (int w = 0; w < wv; ++w) off += wcnt[w];
                int rank = off + __popcll(m & ((1ull << lane) - 1ull));
                if (eq && rank < need)
                    buf[cgt + rank] = compose(K, a);
                __syncthreads();
                if (tid == 0) {
                    int s = 0;
                    for (int w = 0; w < 8; ++w) s += wcnt[w];
                    eqtaken += s;
                }
                __syncthreads();
            }
        }
    }

    // ---- phase 3: sort desc (composite unique -> total order)
    if (mode == 0) {
        // bitonic-1024 over cand, 512 threads x 2 elements
        for (int k2 = 2; k2 <= NCAND; k2 <<= 1) {
            for (int j = k2 >> 1; j > 0; j >>= 1) {
                __syncthreads();
                for (int i = tid; i < NCAND; i += 512) {
                    int ixj = i ^ j;
                    if (ixj > i) {
                        unsigned long long A = cand[i], B = cand[ixj];
                        bool up = (i & k2) == 0;
                        if (up ? (A < B) : (A > B)) { cand[i] = B; cand[ixj] = A; }
                    }
                }
            }
        }
    } else {
        // bitonic-512 over buf
        for (int k2 = 2; k2 <= KC; k2 <<= 1) {
            for (int j = k2 >> 1; j > 0; j >>= 1) {
                __syncthreads();
                {
                    int i = tid, ixj = i ^ j;
                    if (ixj > i) {
                        unsigned long long A = buf[i], B = buf[ixj];
                        bool up = (i & k2) == 0;
                        if (up ? (A < B) : (A > B)) { buf[i] = B; buf[ixj] = A; }
                    }
                }
            }
        }
    }
    __syncthreads();

    // ---- epilogue: write scores + decode the 512 selected boxes
    {
        const unsigned long long v = (mode == 0) ? cand[tid] : buf[tid];
        const unsigned key = (unsigned)(v >> 32);
        const int a = (int)(0xFFFFFFFFu - (unsigned)(v & 0xFFFFFFFFu));
        top_score[col * KC + tid] = sigmoidf_dev(unkey(key));
        const float4 p4 = *reinterpret_cast<const float4*>(pred + ((size_t)b * NA + a) * 84 + 80);
        sel_boxes[(size_t)col * KC + tid] = decode_box(p4, a, dims);
    }
}

// ---- kernel 3a: NMS suppression-matrix build (SPLIT=8, 512 thr) ----------

__global__ __launch_bounds__(512) void nms_build_kernel(const float4* __restrict__ sel_boxes,
                                                        unsigned long long* __restrict__ maskbuf) {
    const int blk = blockIdx.x;
    const int col = blk >> 3, part = blk & 7;
    const int tid = threadIdx.x, wave = tid >> 6, lane = tid & 63;
    __shared__ float y1[KC], x1[KC], y2[KC], x2[KC], ar[KC];   // 10 KiB

    for (int t = tid; t < KC; t += 512) {
        float4 bx = sel_boxes[(size_t)col * KC + t];
        y1[t] = bx.x; x1[t] = bx.y; y2[t] = bx.z; x2[t] = bx.w;
        ar[t] = __fmul_rn(fmaxf(__fsub_rn(bx.z, bx.x), 0.f),
                          fmaxf(__fsub_rn(bx.w, bx.y), 0.f));
    }
    __syncthreads();

    float jy1[8], jx1[8], jy2[8], jx2[8], jar[8];
    #pragma unroll
    for (int w = 0; w < 8; ++w) {
        int j = (w << 6) + lane;
        jy1[w] = y1[j]; jx1[w] = x1[j]; jy2[w] = y2[j]; jx2[w] = x2[j]; jar[w] = ar[j];
    }

    for (int k = 0; k < 8; ++k) {
        const int i = part + SPLIT * (wave + 8 * k);   // i == part (mod 8), covers 0..511
        const float iy1 = y1[i], ix1 = x1[i], iy2 = y2[i], ix2 = x2[i], iar = ar[i];
        unsigned long long row[8];
        #pragma unroll
        for (int w = 0; w < 8; ++w) {
            unsigned long long m = 0ull;
            if (((w << 6) + 63) > i) {
                const int j = (w << 6) + lane;
                float ih = fmaxf(__fsub_rn(fminf(iy2, jy2[w]), fmaxf(iy1, jy1[w])), 0.f);
                float iw = fmaxf(__fsub_rn(fminf(ix2, jx2[w]), fmaxf(ix1, jx1[w])), 0.f);
                float inter = __fmul_rn(ih, iw);
                float uni = __fsub_rn(__fadd_rn(iar, jar[w]), inter);
                m = __ballot((uni > 0.f) && (inter > __fmul_rn(0.5f, uni)) && (j > i));
            }
            row[w] = m;
        }
        unsigned long long v = row[0];
        v = (lane == 1) ? row[1] : v;
        v = (lane == 2) ? row[2] : v;
        v = (lane == 3) ? row[3] : v;
        v = (lane == 4) ? row[4] : v;
        v = (lane == 5) ? row[5] : v;
        v = (lane == 6) ? row[6] : v;
        v = (lane == 7) ? row[7] : v;
        if (lane < 8) maskbuf[((size_t)col * KC + i) * 8 + lane] = v;
    }
}

// ---- kernel 3b: NMS wave-parallel greedy resolve + compaction (512 thr) --

__global__ __launch_bounds__(512) void nms_resolve_kernel(const float4* __restrict__ sel_boxes,
                                                          const float* __restrict__ top_score,
                                                          const unsigned long long* __restrict__ maskbuf,
                                                          float4* __restrict__ col_boxes,
                                                          float* __restrict__ col_scores) {
    const int col = blockIdx.x;
    const int tid = threadIdx.x, wv = tid >> 6, lane = tid & 63;
    __shared__ unsigned long long mask[KC * 8];      // 32 KiB
    __shared__ float y1[KC], x1[KC], y2[KC], x2[KC], sc[KC];   // 10 KiB
    __shared__ unsigned long long keep0w[8], keepw[8];
    __shared__ int wordpfx[9];
    __shared__ int sel[MPC];

    {
        const unsigned long long* src = maskbuf + (size_t)col * KC * 8;
        for (int m = tid; m < KC * 8; m += 512) mask[m] = src[m];
    }
    {
        const int t = tid;                      // single pass: 512 threads cover KC
        float4 bx = sel_boxes[(size_t)col * KC + t];
        y1[t] = bx.x; x1[t] = bx.y; y2[t] = bx.z; x2[t] = bx.w;
        const float s = top_score[col * KC + t];
        sc[t] = s;
        const unsigned long long m = __ballot(s > 0.05f);
        if (lane == 0) keep0w[t >> 6] = m;
    }
    __syncthreads();

    // greedy resolve, wave 0, 8-lane word-parallel, 8-row prefetch
    if (wv == 0) {
        const int w8 = lane & 7;
        const unsigned long long kww = keep0w[w8];
        unsigned long long remw = 0ull;
        for (int ib = 0; ib < KC; ib += 8) {
            unsigned long long rows[8];
            #pragma unroll
            for (int u = 0; u < 8; ++u) rows[u] = mask[(ib + u) * 8 + w8];
            #pragma unroll
            for (int u = 0; u < 8; ++u) {
                const int i = ib + u, W = i >> 6, t = i & 63;
                const unsigned long long remW = __shfl(remw, W);
                const unsigned long long kwW = __shfl(kww, W);
                if (((kwW >> t) & 1ull) && !((remW >> t) & 1ull)) remw |= rows[u];
            }
        }
        if (lane < 8) keepw[w8] = kww & ~remw;
    }
    __syncthreads();
    if (tid == 0) {
        int s = 0;
        #pragma unroll
        for (int w = 0; w < 8; ++w) { wordpfx[w] = s; s += __popcll(keepw[w]); }
        wordpfx[8] = s;
    }
    __syncthreads();

    const int nkept = wordpfx[8];
    {
        const int t = tid;
        const unsigned long long w = keepw[t >> 6];
        const int l = t & 63;
        const bool kp = (w >> l) & 1ull;
        const int kb = wordpfx[t >> 6] + __popcll(w & ((1ull << l) - 1ull));
        if (kp) {
            if (kb < MPC) sel[kb] = t;
        } else {
            const int nb = t - kb;
            if (nkept + nb < MPC) sel[nkept + nb] = t;
        }
    }
    __syncthreads();
    if (tid < MPC) {
        int t = sel[tid];
        bool kp = (keepw[t >> 6] >> (t & 63)) & 1ull;
        col_scores[col * MPC + tid] = kp ? sc[t] : 0.f;
        col_boxes[col * MPC + tid] = make_float4(y1[t], x1[t], y2[t], x2[t]);
    }
}

// ---- kernel 4: per-batch combine — 1024 threads, register keys -----------

__global__ __launch_bounds__(1024) void combine_kernel(const float4* __restrict__ col_boxes,
                                                       const float* __restrict__ col_scores,
                                                       float* __restrict__ out) {
    const int b = blockIdx.x, tid = threadIdx.x;
    const int wv = tid >> 6, lane = tid & 63;
    __shared__ int hist[256];
    __shared__ unsigned long long cand[128];
    __shared__ int sh3[3];
    __shared__ int gcnt, eqtaken;
    __shared__ int wcnt[16];
    __shared__ int wsc[16];

    const int NTOT = NCLS * MPC;     // 8000
    unsigned sck[8];
    #pragma unroll
    for (int q = 0; q < 8; ++q) {
        const int t = (q << 10) + tid;
        sck[q] = (t < NTOT) ? __float_as_uint(col_scores[b * NTOT + t]) : 0u;
    }

    unsigned prefix = 0;
    int remaining = MT, ceq = 0;
    #pragma unroll 1
    for (int pass = 0; pass < 4; ++pass) {
        const int shift = 24 - 8 * pass;
        const unsigned mdone = pass ? (0xFFFFFFFFu << (shift + 8)) : 0u;
        if (tid < 256) hist[tid] = 0;
        __syncthreads();
        #pragma unroll
        for (int q = 0; q < 8; ++q) {
            const int t = (q << 10) + tid;
            if (t < NTOT && (sck[q] & mdone) == prefix)
                atomicAdd(&hist[(sck[q] >> shift) & 255], 1);
        }
        __syncthreads();
        int lsum = (tid < 256) ? hist[255 - tid] : 0;
        int acc2 = lsum;
        #pragma unroll
        for (int off = 1; off < 64; off <<= 1) {
            int x = __shfl_up(acc2, off);
            if (lane >= off) acc2 += x;
        }
        if (lane == 63) wsc[wv] = acc2;
        __syncthreads();
        int base2 = 0;
        for (int w = 0; w < wv; ++w) base2 += wsc[w];
        int run = base2 + acc2 - lsum;
        if (tid < 256 && run < remaining && remaining <= run + lsum) { sh3[0] = 255 - tid; sh3[1] = run; sh3[2] = lsum; }
        __syncthreads();
        prefix |= ((unsigned)sh3[0]) << shift;
        remaining -= sh3[1];
        ceq = sh3[2];
        __syncthreads();
    }
    const unsigned S = prefix;
    const int cgt = MT - remaining;

    if (tid == 0) { gcnt = 0; eqtaken = 0; }
    if (tid < 128) cand[tid] = 0ull;
    __syncthreads();
    #pragma unroll
    for (int q = 0; q < 8; ++q) {
        const int t = (q << 10) + tid;
        if (t < NTOT && sck[q] > S) {
            int p = atomicAdd(&gcnt, 1);
            cand[p] = ((unsigned long long)sck[q] << 32) |
                      (unsigned long long)(0xFFFFFFFFu - (unsigned)t);
        }
    }
    __syncthreads();

    if (ceq == remaining) {
        #pragma unroll
        for (int q = 0; q < 8; ++q) {
            const int t = (q << 10) + tid;
            if (t < NTOT && sck[q] == S) {
                int p = atomicAdd(&eqtaken, 1);
                cand[cgt + p] = ((unsigned long long)S << 32) |
                                (unsigned long long)(0xFFFFFFFFu - (unsigned)t);
            }
        }
        __syncthreads();
    } else {
        #pragma unroll 1
        for (int q = 0; q < 8; ++q) {
            const int t = (q << 10) + tid;
            const bool eq = (t < NTOT) && (sck[q] == S);
            unsigned long long m = __ballot(eq);
            if (lane == 0) wcnt[wv] = __popcll(m);
            __syncthreads();
            int off = eqtaken;
            for (int w = 0; w < wv; ++w) off += wcnt[w];
            int rank = off + __popcll(m & ((1ull << lane) - 1ull));
            if (eq && rank < remaining)
                cand[cgt + rank] = ((unsigned long long)S << 32) |
                                   (unsigned long long)(0xFFFFFFFFu - (unsigned)t);
            __syncthreads();
            if (tid == 0) {
                int s = 0;
                for (int w = 0; w < 16; ++w) s += wcnt[w];
                eqtaken += s;
            }
            __syncthreads();
        }
    }

    for (int k2 = 2; k2 <= 128; k2 <<= 1) {
        for (int j = k2 >> 1; j > 0; j >>= 1) {
            __syncthreads();
            if (tid < 128) {
                int i = tid, ixj = i ^ j;
                if (ixj > i) {
                    unsigned long long A = cand[i], B = cand[ixj];
                    bool up = (i & k2) == 0;
                    if (up ? (A < B) : (A > B)) { cand[i] = B; cand[ixj] = A; }
                }
            }
        }
    }
    __syncthreads();
    if (tid == 0) gcnt = 0;
    __syncthreads();
    if (tid < MT) {
        unsigned long long v = cand[tid];
        float s = __uint_as_float((unsigned)(v >> 32));
        int f = (int)(0xFFFFFFFFu - (unsigned)(v & 0xFFFFFFFFu));
        bool valid = (s > 0.f);
        int cl = 0, p = 0;
        float4 bx = make_float4(0.f, 0.f, 0.f, 0.f);
        if (valid) {
            cl = f / MPC;
            p = f - cl * MPC;
            float4 raw = col_boxes[((size_t)b * NCLS + cl) * MPC + p];
            bx.x = fminf(fmaxf(raw.x, 0.f), 1.f);
            bx.y = fminf(fmaxf(raw.y, 0.f), 1.f);
            bx.z = fminf(fmaxf(raw.z, 0.f), 1.f);
            bx.w = fminf(fmaxf(raw.w, 0.f), 1.f);
            atomicAdd(&gcnt, 1);
        }
        int o = b * MT + tid;
        out[o * 4 + 0] = bx.x;
        out[o * 4 + 1] = bx.y;
        out[o * 4 + 2] = bx.z;
        out[o * 4 + 3] = bx.w;
        out[NB * MT * 4 + o] = valid ? s : 0.f;
        out[NB * MT * 5 + o] = valid ? (float)cl : 0.f;
    }
    __syncthreads();
    if (tid == 0) out[NB * MT * 6 + b] = (float)gcnt;
}

// ---- launch --------------------------------------------------------------

extern "C" void kernel_launch(void* const* d_in, const int* in_sizes, int n_in,
                              void* d_out, int out_size, void* d_ws, size_t ws_size,
                              hipStream_t stream) {
    const float* pred = (const float*)d_in[1];
    float* out = (float*)d_out;
    char* ws = (char*)d_ws;

    Dims dims;
    const double ratios[3] = {0.5, 1.0, 2.0};
    for (int l = 0; l < 5; ++l) {
        double side = (double)(1 << (l + 5));
        double area = side * side;
        for (int ri = 0; ri < 3; ++ri) {
            double ah = sqrt(area / ratios[ri]);
            double aw = area / ah;
            for (int si = 0; si < 3; ++si) {
                double s = pow(2.0, (double)si / 3.0);
                dims.d[(l * 9 + ri * 3 + si) * 2 + 0] = (float)(s * aw);
                dims.d[(l * 9 + ri * 3 + si) * 2 + 1] = (float)(s * ah);
            }
        }
    }

    const size_t SZ_CAND = (size_t)NB * NCLS * NSLOTP * SLOT * 8;   // 12,288,000
    const size_t SZ_CNT  = (size_t)NB * NCLS * NSLOTP * 4;          //     384,000
    const size_t SZ_SC   = (size_t)NB * NCLS * KC * 4;              //     655,360
    const size_t SZ_SEL  = (size_t)NB * NCLS * KC * 16;             //   2,621,440
    const size_t SZ_CB   = (size_t)NB * NCLS * MPC * 16;            //     512,000

    unsigned long long* candbuf    = (unsigned long long*)(ws);
    int*                counts2    = (int*)(ws + SZ_CAND);
    float*              top_score  = (float*)(ws + SZ_CAND + SZ_CNT);
    float4*             sel_boxes  = (float4*)(ws + SZ_CAND + SZ_CNT + SZ_SC);
    float4*             col_boxes  = (float4*)(ws + SZ_CAND + SZ_CNT + SZ_SC + SZ_SEL);
    float*              col_scores = (float*)(ws + SZ_CAND + SZ_CNT + SZ_SC + SZ_SEL + SZ_CB);
    // maskbuf (10.48 MB) aliases candbuf (12.29 MB) — candidates dead after topk2.
    unsigned long long* maskbuf    = (unsigned long long*)(ws);

    scan_kernel<<<NB * NTILE, 256, 0, stream>>>(pred, candbuf, counts2);
    topk2_kernel<<<NB * NCLS, 512, 0, stream>>>(pred, candbuf, counts2, top_score, sel_boxes, dims);
    nms_build_kernel<<<NB * NCLS * SPLIT, 512, 0, stream>>>(sel_boxes, maskbuf);
    nms_resolve_kernel<<<NB * NCLS, 512, 0, stream>>>(sel_boxes, top_score, maskbuf, col_boxes, col_scores);
    combine_kernel<<<NB, 1024, 0, stream>>>(col_boxes, col_scores, out);
}